// Round 2
// baseline (638.889 us; speedup 1.0000x reference)
//
#include <hip/hip_runtime.h>

typedef unsigned int u32;
typedef unsigned short u16;
typedef unsigned long long u64;
typedef _Float16 f16;
typedef _Float16 f16x2 __attribute__((ext_vector_type(2)));

#define Bn 256
#define Sn 200
#define Dn 128
#define Mn 64
#define NQn 5000

__device__ __forceinline__ float fdot2f(u32 w, u32 x, float acc) {
#if __has_builtin(__builtin_amdgcn_fdot2)
    return __builtin_amdgcn_fdot2(__builtin_bit_cast(f16x2, w),
                                  __builtin_bit_cast(f16x2, x), acc, false);
#else
    f16x2 a = __builtin_bit_cast(f16x2, w);
    f16x2 b = __builtin_bit_cast(f16x2, x);
    return acc + (float)a[0] * (float)b[0] + (float)a[1] * (float)b[1];
#endif
}

__device__ __forceinline__ u32 packh2(float a, float b) {
    u16 ua = __builtin_bit_cast(u16, (f16)a);
    u16 ub = __builtin_bit_cast(u16, (f16)b);
    return (u32)ua | ((u32)ub << 16);
}

__device__ __forceinline__ float h2f(u16 u) { return (float)__builtin_bit_cast(f16, u); }

__device__ __forceinline__ float fexp2f(float x) {
#if __has_builtin(__builtin_amdgcn_exp2f)
    return __builtin_amdgcn_exp2f(x);
#else
    return exp2f(x);
#endif
}
__device__ __forceinline__ float frcpf(float x) {
#if __has_builtin(__builtin_amdgcn_rcpf)
    return __builtin_amdgcn_rcpf(x);
#else
    return 1.0f / x;
#endif
}
__device__ __forceinline__ float sig_fast(float x)  { return frcpf(1.0f + fexp2f(-1.44269504f * x)); }
__device__ __forceinline__ float tanh_fast(float x) { return fmaf(-2.0f, frcpf(1.0f + fexp2f(2.88539008f * x)), 1.0f); }

// ---------------------------------------------------------------------------
// Kernel A: per (b,s): cw = softmax(k @ Mk^T) (fp32), store cw f16 + iv codes.
// (unchanged, passing)
// ---------------------------------------------------------------------------
__global__ __launch_bounds__(512) void phase0_kernel(
    const int* __restrict__ qseq,
    const float* __restrict__ Mk, const float* __restrict__ embc,
    u16* __restrict__ cw16, ulonglong2* __restrict__ codes)
{
    __shared__ float MkT[Dn * 65];
    __shared__ float kb[8][Dn];
    int tid = threadIdx.x;
    for (int idx = tid; idx < Mn * Dn; idx += 512) {
        int m = idx >> 7, d = idx & 127;
        MkT[d * 65 + m] = Mk[idx];
    }
    __syncthreads();
    int w = tid >> 6, lane = tid & 63;
    int item = blockIdx.x * 8 + w;
    int qq = qseq[item];
    kb[w][lane]      = embc[qq * Dn + lane];
    kb[w][lane + 64] = embc[qq * Dn + lane + 64];
    __syncthreads();
    float acc = 0.0f;
    const float* kw = kb[w];
#pragma unroll 8
    for (int d = 0; d < Dn; ++d)
        acc = fmaf(MkT[d * 65 + lane], kw[d], acc);
    float mx = acc;
    for (int off = 32; off; off >>= 1) mx = fmaxf(mx, __shfl_xor(mx, off));
    float e = expf(acc - mx);
    float sm = e;
    for (int off = 32; off; off >>= 1) sm += __shfl_xor(sm, off);
    float cw = e / sm;
    cw16[item * Mn + lane] = __builtin_bit_cast(u16, (f16)cw);
    float t1 = (cw - 0.01f) / (0.05f - 0.01f);
    float t2 = (0.1f - cw) / (0.1f - 0.05f);
    float tri = fminf(t1, t2);
    tri = fmaxf(tri, 0.0f);
    int iv = (tri >= 0.6f) ? 2 : ((tri >= 0.1f) ? 1 : 0);
    u64 b1 = __ballot(iv >= 1);
    u64 b2 = __ballot(iv == 2);
    if (lane == 0) { codes[item].x = b1; codes[item].y = b2; }
}

// ---------------------------------------------------------------------------
// Kernel B: prev_t match. (unchanged)
// ---------------------------------------------------------------------------
__global__ __launch_bounds__(256) void match_kernel(
    const ulonglong2* __restrict__ codes, int* __restrict__ prev)
{
    __shared__ u64 clo[Sn], chi[Sn];
    int b = blockIdx.x, tid = threadIdx.x;
    if (tid < Sn) { ulonglong2 c = codes[b * Sn + tid]; clo[tid] = c.x; chi[tid] = c.y; }
    __syncthreads();
    if (tid < Sn) {
        u64 mylo = clo[tid], myhi = chi[tid];
        int best = -1;
        for (int j = 0; j < tid; ++j)
            if (clo[j] == mylo && chi[j] == myhi) best = j;
        prev[b * Sn + tid] = best;
    }
}

// ---------------------------------------------------------------------------
// Kernel S: composite matrices (fp32 in ws).
//   CEf = We  @ Wa[:, :128]   CEy = We  @ Wa[:, 128:]
//   CAf = Wadd@ Wa[:, :128]   CAy = Wadd@ Wa[:, 128:]
//   c0s[0:128]   = We  @ ba + be
//   c0s[128:256] = Wadd@ ba + badd
// One block per output row d; 512 threads = 4 mats x 128 cols.
// ---------------------------------------------------------------------------
__global__ __launch_bounds__(512) void setup_kernel(
    const float* __restrict__ Wa, const float* __restrict__ We,
    const float* __restrict__ Wadd,
    const float* __restrict__ ba, const float* __restrict__ be,
    const float* __restrict__ badd,
    float* __restrict__ CEf, float* __restrict__ CAf,
    float* __restrict__ CEy, float* __restrict__ CAy,
    float* __restrict__ c0s)
{
    __shared__ float weR[128], waR[128];
    int d = blockIdx.x, tid = threadIdx.x;
    if (tid < 128) weR[tid] = We[d * 128 + tid];
    else if (tid < 256) waR[tid - 128] = Wadd[d * 128 + (tid - 128)];
    __syncthreads();
    int mat = tid >> 7, j = tid & 127;
    const float* src = (mat == 0 || mat == 2) ? weR : waR;
    int col = (mat < 2) ? j : (128 + j);
    float acc = 0.0f;
    for (int k = 0; k < 128; ++k) acc = fmaf(src[k], Wa[k * 256 + col], acc);
    float* dst = (mat == 0) ? CEf : (mat == 1) ? CAf : (mat == 2) ? CEy : CAy;
    dst[d * 128 + j] = acc;
    if (tid == 0) {
        float a = 0.0f;
        for (int k = 0; k < 128; ++k) a = fmaf(weR[k], ba[k], a);
        c0s[d] = a + be[d];
    } else if (tid == 1) {
        float a = 0.0f;
        for (int k = 0; k < 128; ++k) a = fmaf(waR[k], ba[k], a);
        c0s[128 + d] = a + badd[d];
    }
}

// ---------------------------------------------------------------------------
// Kernel Rk: per-ROW kf table (5000 rows, not 51200 items):
//   kfR[r][d] = sum_j Wf[d][128+j] * embc[r][j]
// ---------------------------------------------------------------------------
__global__ __launch_bounds__(512) void rowk_kernel(
    const float* __restrict__ W, const float* __restrict__ emb,
    u16* __restrict__ outp)
{
    __shared__ u32 wL[128 * 65];
    __shared__ u32 vb[8][64];
    int tid = threadIdx.x;
    for (int idx = tid; idx < 128 * 64; idx += 512) {
        int dd = idx >> 6, jj = idx & 63;
        const float2 wv = *(const float2*)(W + dd * 256 + 128 + 2 * jj);
        wL[dd * 65 + jj] = packh2(wv.x, wv.y);
    }
    int w = tid >> 6, lane = tid & 63;
    int row = blockIdx.x * 8 + w;          // grid is exact: 5000/8 = 625
    {
        const float2 kv = *(const float2*)(emb + row * Dn + 2 * lane);
        vb[w][lane] = packh2(kv.x, kv.y);
    }
    __syncthreads();
    const u32* w0 = wL + lane * 65;
    const u32* w1 = wL + (64 + lane) * 65;
    const u32* x  = vb[w];
    float a0 = 0, a1 = 0, b0 = 0, b1 = 0;
#pragma unroll
    for (int jj = 0; jj < 64; jj += 2) {
        a0 = fdot2f(w0[jj],     x[jj],     a0);
        a1 = fdot2f(w0[jj + 1], x[jj + 1], a1);
        b0 = fdot2f(w1[jj],     x[jj],     b0);
        b1 = fdot2f(w1[jj + 1], x[jj + 1], b1);
    }
    outp[row * Dn + lane]      = __builtin_bit_cast(u16, (f16)(a0 + a1));
    outp[row * Dn + 64 + lane] = __builtin_bit_cast(u16, (f16)(b0 + b1));
}

// ---------------------------------------------------------------------------
// Kernel Re: per-ROW erase/add offset tables (10000 interaction rows):
//   ebR[r][d] = CEy[d]@embi[r] + c0s[d]
//   abR[r][d] = CAy[d]@embi[r] + c0s[128+d]
// ---------------------------------------------------------------------------
__global__ __launch_bounds__(512) void rowe_kernel(
    const float* __restrict__ CEy, const float* __restrict__ CAy,
    const float* __restrict__ c0s, const float* __restrict__ embi,
    u16* __restrict__ ebR, u16* __restrict__ abR)
{
    __shared__ u32 eL[128 * 65];
    __shared__ u32 aL[128 * 65];
    __shared__ u32 vb[8][64];
    __shared__ float c0L[256];
    int tid = threadIdx.x;
    for (int idx = tid; idx < 128 * 64; idx += 512) {
        int dd = idx >> 6, jj = idx & 63;
        const float2 e2 = *(const float2*)(CEy + dd * 128 + 2 * jj);
        const float2 a2 = *(const float2*)(CAy + dd * 128 + 2 * jj);
        eL[dd * 65 + jj] = packh2(e2.x, e2.y);
        aL[dd * 65 + jj] = packh2(a2.x, a2.y);
    }
    if (tid < 256) c0L[tid] = c0s[tid];
    int w = tid >> 6, lane = tid & 63;
    int row = blockIdx.x * 8 + w;          // grid exact: 10000/8 = 1250
    {
        const float2 kv = *(const float2*)(embi + row * Dn + 2 * lane);
        vb[w][lane] = packh2(kv.x, kv.y);
    }
    __syncthreads();
    const u32* x   = vb[w];
    const u32* e0p = eL + lane * 65;
    const u32* e1p = eL + (64 + lane) * 65;
    const u32* a0p = aL + lane * 65;
    const u32* a1p = aL + (64 + lane) * 65;
    float ea0 = 0, ea1 = 0, eb0 = 0, eb1 = 0;
    float aa0 = 0, aa1 = 0, ab0 = 0, ab1 = 0;
#pragma unroll
    for (int jj = 0; jj < 64; jj += 2) {
        ea0 = fdot2f(e0p[jj],     x[jj],     ea0);
        ea1 = fdot2f(e0p[jj + 1], x[jj + 1], ea1);
        eb0 = fdot2f(e1p[jj],     x[jj],     eb0);
        eb1 = fdot2f(e1p[jj + 1], x[jj + 1], eb1);
        aa0 = fdot2f(a0p[jj],     x[jj],     aa0);
        aa1 = fdot2f(a0p[jj + 1], x[jj + 1], aa1);
        ab0 = fdot2f(a1p[jj],     x[jj],     ab0);
        ab1 = fdot2f(a1p[jj + 1], x[jj + 1], ab1);
    }
    ebR[row * Dn + lane]      = __builtin_bit_cast(u16, (f16)(ea0 + ea1 + c0L[lane]));
    ebR[row * Dn + 64 + lane] = __builtin_bit_cast(u16, (f16)(eb0 + eb1 + c0L[64 + lane]));
    abR[row * Dn + lane]      = __builtin_bit_cast(u16, (f16)(aa0 + aa1 + c0L[128 + lane]));
    abR[row * Dn + 64 + lane] = __builtin_bit_cast(u16, (f16)(ab0 + ab1 + c0L[192 + lane]));
}

// ---------------------------------------------------------------------------
// Kernel C: DKVMN value-memory recurrence — 2 barriers/step (was 3).
// erase/add computed directly from f via composite matrices CEf/CAf;
// per-(b,t) offsets ebc/abc gathered per-row into LDS chunks.
// thread -> (d = tid>>2, q = tid&3). One block (512 thr) per b.
// ---------------------------------------------------------------------------
__global__ __launch_bounds__(512, 2) void memrec_kernel(
    const float* __restrict__ Mv0,
    const float* __restrict__ Wf, const float* __restrict__ bfv,
    const float* __restrict__ CEf, const float* __restrict__ CAf,
    const u16* __restrict__ cw16, const u16* __restrict__ kfR,
    const u16* __restrict__ ebR, const u16* __restrict__ abR,
    const int* __restrict__ qseq, const int* __restrict__ cseq,
    u16* __restrict__ ft16)
{
    __shared__ u32 cwL[Sn * 32];                    // 25.6 KB: all-t cw (f16 pairs)
    __shared__ __align__(16) u32 kfb[2][16 * 64];   // 8 KB dbuf chunks
    __shared__ __align__(16) u32 ebb[2][16 * 64];
    __shared__ __align__(16) u32 abb[2][16 * 64];
    __shared__ __align__(16) u32 rbuf[64], fbuf[64];
    __shared__ float bfL[Dn];
    __shared__ int qrowL[Sn], irowL[Sn];

    int tid = threadIdx.x;
    int d = tid >> 2, q = tid & 3;
    int b = blockIdx.x;

    u32 wfr[16], wew[16], wadw[16];
    {
        const float2* wf2 = (const float2*)(Wf  + d * 256 + q * 32);
        const float2* we2 = (const float2*)(CEf + d * 128 + q * 32);
        const float2* wd2 = (const float2*)(CAf + d * 128 + q * 32);
#pragma unroll
        for (int i = 0; i < 16; ++i) {
            float2 a;
            a = wf2[i]; wfr[i]  = packh2(a.x, a.y);
            a = we2[i]; wew[i]  = packh2(a.x, a.y);
            a = wd2[i]; wadw[i] = packh2(a.x, a.y);
        }
    }
    float memv[16];
#pragma unroll
    for (int i = 0; i < 16; ++i) memv[i] = Mv0[(q * 16 + i) * Dn + d];

    if (tid < Dn) bfL[tid] = bfv[tid];
    if (tid < Sn) {
        int qq = qseq[b * Sn + tid];
        qrowL[tid] = qq;
        irowL[tid] = qq + NQn * cseq[b * Sn + tid];
    }
    __syncthreads();                                 // row ids ready for staging

    for (int i = tid; i < Sn * 32; i += 512) cwL[i] = ((const u32*)cw16)[b * Sn * 32 + i];
    for (int i = tid; i < 1024; i += 512) {          // stage chunk 0
        int s = i >> 6, off = i & 63;
        kfb[0][i] = ((const u32*)kfR)[qrowL[s] * 64 + off];
        ebb[0][i] = ((const u32*)ebR)[irowL[s] * 64 + off];
        abb[0][i] = ((const u32*)abR)[irowL[s] * 64 + off];
    }
    __syncthreads();

    float cwreg[16];
#pragma unroll
    for (int i = 0; i < 8; ++i) {
        u32 v = cwL[q * 8 + i];
        cwreg[2 * i]     = h2f((u16)(v & 0xffff));
        cwreg[2 * i + 1] = h2f((u16)(v >> 16));
    }

    for (int t = 0; t < Sn; ++t) {
        int sl = (t >> 4) & 1, ti = t & 15;
        if (ti == 0) {                               // stage next 16-step chunk
            int c1 = (t >> 4) + 1;
            if (c1 * 16 < Sn) {
                int n = (Sn - c1 * 16 < 16 ? Sn - c1 * 16 : 16) * 64;
                for (int i = tid; i < n; i += 512) {
                    int s = i >> 6, off = i & 63;
                    int t2 = c1 * 16 + s;
                    kfb[sl ^ 1][i] = ((const u32*)kfR)[qrowL[t2] * 64 + off];
                    ebb[sl ^ 1][i] = ((const u32*)ebR)[irowL[t2] * 64 + off];
                    abb[sl ^ 1][i] = ((const u32*)abR)[irowL[t2] * 64 + off];
                }
            }
        }
        // ---- P1: read partial -------------------------------------------
        float p0 = 0, p1 = 0, p2 = 0, p3 = 0;
#pragma unroll
        for (int i = 0; i < 4; ++i) {
            p0 = fmaf(cwreg[i],      memv[i],      p0);
            p1 = fmaf(cwreg[4 + i],  memv[4 + i],  p1);
            p2 = fmaf(cwreg[8 + i],  memv[8 + i],  p2);
            p3 = fmaf(cwreg[12 + i], memv[12 + i], p3);
        }
        float pr = (p0 + p1) + (p2 + p3);
        pr += __shfl_xor(pr, 1);
        pr += __shfl_xor(pr, 2);
        if (q == 0) ((f16*)rbuf)[d] = (f16)pr;
        __syncthreads();                                        // B1
        // ---- P2: f = tanh(Wf_r @ read + kf_t + bf); also pull chunk regs
        u16 kfc = ((const u16*)(kfb[sl]))[ti * 128 + d];
        u16 ebc = ((const u16*)(ebb[sl]))[ti * 128 + d];
        u16 abc = ((const u16*)(abb[sl]))[ti * 128 + d];
        float a0 = 0, a1 = 0, a2 = 0, a3 = 0;
#pragma unroll
        for (int u = 0; u < 4; ++u) {
            uint4 x = ((const uint4*)rbuf)[(q << 2) + u];
            a0 = fdot2f(wfr[4 * u + 0], x.x, a0);
            a1 = fdot2f(wfr[4 * u + 1], x.y, a1);
            a2 = fdot2f(wfr[4 * u + 2], x.z, a2);
            a3 = fdot2f(wfr[4 * u + 3], x.w, a3);
        }
        float accf = (a0 + a1) + (a2 + a3);
        accf += __shfl_xor(accf, 1);
        accf += __shfl_xor(accf, 2);
        float fv = tanh_fast(accf + h2f(kfc) + bfL[d]);
        if (q == 0) ((f16*)fbuf)[d] = (f16)fv;
        if (q == 1) ft16[(size_t)(b * Sn + t) * Dn + d] = __builtin_bit_cast(u16, (f16)fv);
        __syncthreads();                                        // B2
        // ---- P3': erase/add straight from f (composite), mem update -----
        float e0 = 0, e1 = 0, g0 = 0, g1 = 0;
#pragma unroll
        for (int u = 0; u < 4; ++u) {
            uint4 x = ((const uint4*)fbuf)[(q << 2) + u];
            e0 = fdot2f(wew[4 * u + 0], x.x, e0);   g0 = fdot2f(wadw[4 * u + 0], x.x, g0);
            e1 = fdot2f(wew[4 * u + 1], x.y, e1);   g1 = fdot2f(wadw[4 * u + 1], x.y, g1);
            e0 = fdot2f(wew[4 * u + 2], x.z, e0);   g0 = fdot2f(wadw[4 * u + 2], x.z, g0);
            e1 = fdot2f(wew[4 * u + 3], x.w, e1);   g1 = fdot2f(wadw[4 * u + 3], x.w, g1);
        }
        float pe = e0 + e1, pa = g0 + g1;
        pe += __shfl_xor(pe, 1); pe += __shfl_xor(pe, 2);
        pa += __shfl_xor(pa, 1); pa += __shfl_xor(pa, 2);
        float ev = sig_fast(pe + h2f(ebc));
        float av = tanh_fast(pa + h2f(abc));
        u32 cwn[8];
        if (t + 1 < Sn) {
#pragma unroll
            for (int i = 0; i < 8; ++i) cwn[i] = cwL[(t + 1) * 32 + q * 8 + i];
        }
#pragma unroll
        for (int i = 0; i < 16; ++i) {
            float tt = fmaf(-ev, memv[i], av);      // add - erase*mem
            memv[i] = fmaf(cwreg[i], tt, memv[i]);
        }
        if (t + 1 < Sn) {
#pragma unroll
            for (int i = 0; i < 8; ++i) {
                cwreg[2 * i]     = h2f((u16)(cwn[i] & 0xffff));
                cwreg[2 * i + 1] = h2f((u16)(cwn[i] >> 16));
            }
        }
        // no barrier here: next step's B1 protects fbuf WAR; chunk reads
        // were pulled into regs before B2, so staging at next ti==0 is safe.
    }
}

// ---------------------------------------------------------------------------
// Kernel D: hop-LSTM — quad-split, ONE barrier/step (was 2).
// thread (d = tid>>2, q = tid&3) computes quarter-partials of all 4 gates,
// shfl_xor reduce over q, redundant activations (bitwise identical per q).
// ---------------------------------------------------------------------------
__global__ __launch_bounds__(512, 2) void lstm_kernel(
    const float* __restrict__ W_ih, const float* __restrict__ W_hh,
    const float* __restrict__ b_ih, const float* __restrict__ b_hh,
    const float* __restrict__ hx0, const float* __restrict__ cx0,
    const float* __restrict__ Wp, const float* __restrict__ bp,
    const u16* __restrict__ ft16, const int* __restrict__ prev,
    float* __restrict__ out)
{
    __shared__ __align__(16) u32 HL[(Sn + 1) * 64];   // 51.4 KB: h history f16
    __shared__ __align__(16) u32 ftb[2][16 * 64];     // 8 KB: ft chunk dbuf
    __shared__ int prevL[Sn];
    __shared__ u32 wpL[64];
    __shared__ float bpL;

    int tid = threadIdx.x, b = blockIdx.x;
    int d = tid >> 2, q = tid & 3;
    u32 wx[4][16], wh[4][16];
    float bias[4];
#pragma unroll
    for (int g = 0; g < 4; ++g) {
        const float2* wi2 = (const float2*)(W_ih + (size_t)(g * 128 + d) * Dn + q * 32);
        const float2* wh2 = (const float2*)(W_hh + (size_t)(g * 128 + d) * Dn + q * 32);
#pragma unroll
        for (int i = 0; i < 16; ++i) {
            float2 a;
            a = wi2[i]; wx[g][i] = packh2(a.x, a.y);
            a = wh2[i]; wh[g][i] = packh2(a.x, a.y);
        }
        bias[g] = b_ih[g * 128 + d] + b_hh[g * 128 + d];
    }
    if (tid < 64) {
        HL[tid]  = packh2(hx0[2 * tid], hx0[2 * tid + 1]);
        wpL[tid] = packh2(Wp[2 * tid], Wp[2 * tid + 1]);
    }
    if (tid < Sn) prevL[tid] = prev[b * Sn + tid];
    if (tid == 0) bpL = bp[0];
    float cx = cx0[d];
    {
        const u32* fg = (const u32*)ft16 + (size_t)(b * Sn) * 64;
        for (int i = tid; i < 1024; i += 512) ftb[0][i] = fg[i];
    }
    __syncthreads();

    for (int t = 0; t < Sn; ++t) {
        int sl = (t >> 4) & 1, ti = t & 15;
        if (ti == 0) {
            int c1 = (t >> 4) + 1;
            if (c1 * 16 < Sn) {
                int n = (Sn - c1 * 16 < 16 ? Sn - c1 * 16 : 16) * 64;
                const u32* fg = (const u32*)ft16 + (size_t)(b * Sn + c1 * 16) * 64;
                for (int i = tid; i < n; i += 512) ftb[sl ^ 1][i] = fg[i];
            }
        }
        int pv = prevL[t];
        int hrow = (pv >= 0) ? (pv + 1) : t;
        const uint4* h4 = (const uint4*)(HL + hrow * 64 + q * 16);
        const uint4* f4 = (const uint4*)(ftb[sl] + ti * 64 + q * 16);
        uint4 xv[4], yv[4];
#pragma unroll
        for (int u = 0; u < 4; ++u) { xv[u] = f4[u]; yv[u] = h4[u]; }
        float gacc[4];
#pragma unroll
        for (int g = 0; g < 4; ++g) {
            float s0 = 0, s1 = 0, s2 = 0, s3 = 0;
#pragma unroll
            for (int u = 0; u < 4; ++u) {
                s0 = fdot2f(wx[g][4 * u + 0], xv[u].x, s0);
                s1 = fdot2f(wx[g][4 * u + 1], xv[u].y, s1);
                s2 = fdot2f(wx[g][4 * u + 2], xv[u].z, s2);
                s3 = fdot2f(wx[g][4 * u + 3], xv[u].w, s3);
                s0 = fdot2f(wh[g][4 * u + 0], yv[u].x, s0);
                s1 = fdot2f(wh[g][4 * u + 1], yv[u].y, s1);
                s2 = fdot2f(wh[g][4 * u + 2], yv[u].z, s2);
                s3 = fdot2f(wh[g][4 * u + 3], yv[u].w, s3);
            }
            float s = (s0 + s1) + (s2 + s3);
            s += __shfl_xor(s, 1);
            s += __shfl_xor(s, 2);
            gacc[g] = s + bias[g];
        }
        float ig = sig_fast(gacc[0]);
        float fgt = sig_fast(gacc[1]);
        float gg = tanh_fast(gacc[2]);
        float og = sig_fast(gacc[3]);
        cx = fmaf(fgt, cx, ig * gg);
        float h = og * tanh_fast(cx);
        if (q == 0) ((f16*)HL)[(t + 1) * Dn + d] = (f16)h;
        __syncthreads();                           // single barrier per step
    }
    if (tid < Sn) {
        float acc = 0.0f;
        const u32* hr = HL + (tid + 1) * 64;
#pragma unroll 16
        for (int j = 0; j < 64; ++j) acc = fdot2f(hr[j], wpL[j], acc);
        out[b * Sn + tid] = sig_fast(acc + bpL);
    }
}

// ---------------------------------------------------------------------------
extern "C" void kernel_launch(void* const* d_in, const int* in_sizes, int n_in,
                              void* d_out, int out_size, void* d_ws, size_t ws_size,
                              hipStream_t stream) {
    const int*   qseq = (const int*)d_in[0];
    const int*   cseq = (const int*)d_in[1];
    const float* Mk   = (const float*)d_in[2];
    const float* Mv0  = (const float*)d_in[3];
    const float* embc = (const float*)d_in[4];
    const float* embi = (const float*)d_in[5];
    const float* Wf   = (const float*)d_in[6];
    const float* bfv  = (const float*)d_in[7];
    const float* Wa   = (const float*)d_in[8];
    const float* bav  = (const float*)d_in[9];
    const float* We   = (const float*)d_in[10];
    const float* bev  = (const float*)d_in[11];
    const float* Wadd = (const float*)d_in[12];
    const float* badv = (const float*)d_in[13];
    const float* W_ih = (const float*)d_in[14];
    const float* W_hh = (const float*)d_in[15];
    const float* b_ih = (const float*)d_in[16];
    const float* b_hh = (const float*)d_in[17];
    const float* hx0  = (const float*)d_in[18];
    const float* cx0  = (const float*)d_in[19];
    const float* Wp   = (const float*)d_in[20];
    const float* bp   = (const float*)d_in[21];
    float* out = (float*)d_out;

    char* ws = (char*)d_ws;
    u16* cw16 = (u16*)ws;                              //  0          + 6,553,600
    u16* ft16 = (u16*)(ws + 6553600);                  //  6,553,600  +13,107,200
    ulonglong2* codes = (ulonglong2*)(ws + 19660800);  // 19,660,800  +   819,200
    int* prev = (int*)(ws + 20480000);                 // 20,480,000  +   204,800
    u16* kfR  = (u16*)(ws + 20684800);                 // 20,684,800  + 1,280,000
    u16* ebR  = (u16*)(ws + 21964800);                 // 21,964,800  + 2,560,000
    u16* abR  = (u16*)(ws + 24524800);                 // 24,524,800  + 2,560,000
    float* CEf = (float*)(ws + 27084800);              // 27,084,800  +    65,536
    float* CAf = (float*)(ws + 27150336);              //             +    65,536
    float* CEy = (float*)(ws + 27215872);              //             +    65,536
    float* CAy = (float*)(ws + 27281408);              //             +    65,536
    float* c0s = (float*)(ws + 27346944);              //             +     1,024 -> 27.35 MB

    setup_kernel<<<128, 512, 0, stream>>>(Wa, We, Wadd, bav, bev, badv,
                                          CEf, CAf, CEy, CAy, c0s);
    phase0_kernel<<<(Bn * Sn) / 8, 512, 0, stream>>>(qseq, Mk, embc, cw16, codes);
    rowk_kernel<<<NQn / 8, 512, 0, stream>>>(Wf, embc, kfR);
    rowe_kernel<<<(2 * NQn) / 8, 512, 0, stream>>>(CEy, CAy, c0s, embi, ebR, abR);
    match_kernel<<<Bn, 256, 0, stream>>>(codes, prev);
    memrec_kernel<<<Bn, 512, 0, stream>>>(Mv0, Wf, bfv, CEf, CAf,
                                          cw16, kfR, ebR, abR, qseq, cseq, ft16);
    lstm_kernel<<<Bn, 512, 0, stream>>>(W_ih, W_hh, b_ih, b_hh, hx0, cx0, Wp, bp,
                                        ft16, prev, out);
}